// Round 22
// baseline (132.221 us; speedup 1.0000x reference)
//
#include <hip/hip_runtime.h>

#define IN_DIM 128
#define HID 64
#define SHIFT 8                 // 256 nodes per bucket
#define BNODES 256
#define NBMAX 1024              // NB=391 @ N=100k
#define CH 2048                 // edges per chunk (R22: 4096->2048, NCH=782 = 3 blocks/CU TLP)
#define SRCMASK 0xFFFFF         // src packed in low 20 bits (N <= 1M)
#define LDSCAP 6144             // csr_place LDS edge-staging capacity (48 KB)
#define XSTR 130                // Xs row stride in shorts

using bf16x8 = __attribute__((ext_vector_type(8))) short;   // 8 bf16 (4 VGPRs)
using f32x4  = __attribute__((ext_vector_type(4))) float;
using f32x2  = __attribute__((ext_vector_type(2))) float;

// bf16 round-to-nearest-even
__device__ inline unsigned short f2bf(float f) {
  unsigned u = __float_as_uint(f);
  u += 0x7FFF + ((u >> 16) & 1);
  return (unsigned short)(u >> 16);
}
__device__ inline float bf2f_lo(unsigned v) {   // low bf16 of a packed u32
  return __uint_as_float(v << 16);
}
__device__ inline float bf2f_hi(unsigned v) {   // high bf16 of a packed u32
  return __uint_as_float(v & 0xFFFF0000u);
}
__device__ inline f32x2 unpk2(unsigned v) {     // {lo, hi} as f32 pair
  return (f32x2){bf2f_lo(v), bf2f_hi(v)};
}

// R18: bijective XCD-aware block->chunk remap (kept).
__device__ inline int xcd_chunk(int bid, int nch) {
  int q = nch >> 3, r = nch & 7;
  int xcd = bid & 7, idx = bid >> 3;
  return (xcd < r) ? xcd * (q + 1) + idx : r * (q + 1) + (xcd - r) * q + idx;
}

// ---------------- Prep: pack W1 into MFMA B-fragment order + zero counters ----------------
// R22: separate pack kernel restored (R21's per-block fold made every gemm1
// block redo the uncoalesced 256B-stride W1 read -> net regression).
__global__ __launch_bounds__(256) void w1pack_kernel(
    const float* __restrict__ W1, unsigned short* __restrict__ W1b,
    int* __restrict__ bucket_size, int NB) {
  if (blockIdx.x == 0) {
    for (int i = threadIdx.x; i < NB; i += 256) bucket_size[i] = 0;
  }
  int idx = blockIdx.x * 256 + threadIdx.x;   // 8192 total
  if (idx >= 4 * 4 * 64 * 8) return;
  int i    = idx & 7;
  int lane = (idx >> 3) & 63;
  int kc   = (idx >> 9) & 3;
  int jt   = idx >> 11;
  int k = kc * 32 + ((lane >> 4) << 3) + i;
  int n = jt * 16 + (lane & 15);
  W1b[idx] = f2bf(W1[k * HID + n]);
}

// ---------------- Kernel 1: h1 = bf16(x @ W1 + b1) via MFMA ----------------
// R17/R20 structure (proven): coalesced per-wave LDS staging of x, A-frags
// via ds_read_b128, B-frags from pre-packed W1b (L1-resident, uint4/lane).
__global__ __launch_bounds__(256) void gemm1_kernel(
    const float* __restrict__ x, const unsigned short* __restrict__ W1b,
    const float* __restrict__ b1, unsigned short* __restrict__ h1, int N) {
  __shared__ unsigned short Xs[4][16][XSTR];   // 16.6 KB
  const int lane = threadIdx.x & 63;
  const int w    = threadIdx.x >> 6;           // wave id: rows 16w..16w+15
  const int rblk = blockIdx.x * 64;

  for (int it = 0; it < 8; ++it) {
    int flat = it * 64 + lane;                 // 0..511
    int row  = flat >> 5;                      // 32 float4 per row
    int c4   = (flat & 31) * 4;
    int gr = rblk + w * 16 + row;
    if (gr > N - 1) gr = N - 1;
    float4 v = *reinterpret_cast<const float4*>(x + (long)gr * IN_DIM + c4);
    ushort4 o;
    o.x = f2bf(v.x); o.y = f2bf(v.y); o.z = f2bf(v.z); o.w = f2bf(v.w);
    *reinterpret_cast<ushort4*>(&Xs[w][row][c4]) = o;
  }
  __syncthreads();

  bf16x8 a[4];
#pragma unroll
  for (int kc = 0; kc < 4; ++kc) {
    a[kc] = *reinterpret_cast<const bf16x8*>(
        &Xs[w][lane & 15][kc * 32 + ((lane >> 4) << 3)]);
  }

  const uint4* wb = reinterpret_cast<const uint4*>(W1b);
#pragma unroll
  for (int jt = 0; jt < 4; ++jt) {
    f32x4 acc = {0.f, 0.f, 0.f, 0.f};
#pragma unroll
    for (int kc = 0; kc < 4; ++kc) {
      union { uint4 q; bf16x8 v; } bu;
      bu.q = wb[(jt * 4 + kc) * 64 + lane];
      acc = __builtin_amdgcn_mfma_f32_16x16x32_bf16(a[kc], bu.v, acc, 0, 0, 0);
    }
    const int col = jt * 16 + (lane & 15);
    const float bb = b1[col];
#pragma unroll
    for (int r = 0; r < 4; ++r) {
      int row = (lane >> 4) * 4 + r;
      int gr = rblk + w * 16 + row;
      if (gr < N) h1[(long)gr * HID + col] = f2bf(acc[r] + bb);
    }
  }
}

// ------------- Bucket partition pass 1: per-chunk histogram + reservation -------------
// R21: edst read 4 edges per int4 load.
__global__ __launch_bounds__(256) void bucket_count_kernel(
    const int* __restrict__ dst, int* __restrict__ bucket_size,
    int* __restrict__ blockRel, int NB, int E, int NCH) {
  __shared__ int hist[NBMAX];
  const int c = xcd_chunk(blockIdx.x, NCH);
  for (int i = threadIdx.x; i < NB; i += 256) hist[i] = 0;
  __syncthreads();
  int base = c * CH;
  int end = min(base + CH, E);
  for (int k = base + threadIdx.x * 4; k + 3 < end; k += 1024) {
    int4 d4 = *reinterpret_cast<const int4*>(&dst[k]);
    atomicAdd(&hist[d4.x >> SHIFT], 1);
    atomicAdd(&hist[d4.y >> SHIFT], 1);
    atomicAdd(&hist[d4.z >> SHIFT], 1);
    atomicAdd(&hist[d4.w >> SHIFT], 1);
  }
  int tail_start = base + ((end - base) & ~3);
  for (int k = tail_start + threadIdx.x; k < end; k += 256)
    atomicAdd(&hist[dst[k] >> SHIFT], 1);
  __syncthreads();
  for (int i = threadIdx.x; i < NB; i += 256) {
    int cv = hist[i];
    int r = cv ? atomicAdd(&bucket_size[i], cv) : 0;
    blockRel[(long)c * NB + i] = r;
  }
}

// ------------- Pass 2: exclusive scan of bucket sizes (single block) -------------
__global__ __launch_bounds__(1024) void bucket_scan_kernel(
    const int* __restrict__ bucket_size, int* __restrict__ bucket_offs, int NB) {
  __shared__ int tmp[1024];
  int tid = threadIdx.x;
  int v = (tid < NB) ? bucket_size[tid] : 0;
  tmp[tid] = v;
  __syncthreads();
  for (int off = 1; off < 1024; off <<= 1) {
    int t = (tid >= off) ? tmp[tid - off] : 0;
    __syncthreads();
    tmp[tid] += t;
    __syncthreads();
  }
  if (tid <= NB) bucket_offs[tid] = tmp[tid] - v;  // exclusive; offs[NB]=E
}

// ------------- Pass 3: place edges into bucket-partitioned array -------------
// R21: 4 edges per iteration via int4/float4 loads.
__global__ __launch_bounds__(256) void bucket_place_kernel(
    const int* __restrict__ src, const int* __restrict__ dst,
    const float* __restrict__ w, const int* __restrict__ bucket_offs,
    const int* __restrict__ blockRel, int2* __restrict__ bpart,
    int NB, int E, int NCH) {
  __shared__ int cur[NBMAX];
  const int c = xcd_chunk(blockIdx.x, NCH);
  for (int i = threadIdx.x; i < NB; i += 256)
    cur[i] = bucket_offs[i] + blockRel[(long)c * NB + i];
  __syncthreads();
  int base = c * CH;
  int end = min(base + CH, E);
  for (int k = base + threadIdx.x * 4; k + 3 < end; k += 1024) {
    int4   s4 = *reinterpret_cast<const int4*>(&src[k]);
    int4   d4 = *reinterpret_cast<const int4*>(&dst[k]);
    float4 w4 = *reinterpret_cast<const float4*>(&w[k]);
    int p0 = atomicAdd(&cur[d4.x >> SHIFT], 1);
    int p1 = atomicAdd(&cur[d4.y >> SHIFT], 1);
    int p2 = atomicAdd(&cur[d4.z >> SHIFT], 1);
    int p3 = atomicAdd(&cur[d4.w >> SHIFT], 1);
    bpart[p0] = make_int2((s4.x & SRCMASK) | ((d4.x & (BNODES - 1)) << 20),
                          __float_as_int(w4.x));
    bpart[p1] = make_int2((s4.y & SRCMASK) | ((d4.y & (BNODES - 1)) << 20),
                          __float_as_int(w4.y));
    bpart[p2] = make_int2((s4.z & SRCMASK) | ((d4.z & (BNODES - 1)) << 20),
                          __float_as_int(w4.z));
    bpart[p3] = make_int2((s4.w & SRCMASK) | ((d4.w & (BNODES - 1)) << 20),
                          __float_as_int(w4.w));
  }
  int tail_start = base + ((end - base) & ~3);
  for (int k = tail_start + threadIdx.x; k < end; k += 256) {
    int d = dst[k];
    int b = d >> SHIFT;
    int pos = atomicAdd(&cur[b], 1);
    bpart[pos] = make_int2((src[k] & SRCMASK) | ((d & (BNODES - 1)) << 20),
                           __float_as_int(w[k]));
  }
}

// ------------- Pass 4: per-bucket CSR finalize (LDS-staged) -------------
__global__ __launch_bounds__(256) void csr_place_kernel(
    const int2* __restrict__ bpart, const int* __restrict__ bucket_offs,
    int2* __restrict__ csr, int* __restrict__ noffs, int N, int NB, int E) {
  __shared__ int cnt[BNODES];
  __shared__ int cur[BNODES];
  __shared__ int wtot[4];
  __shared__ int2 ebuf[LDSCAP];
  const int t = threadIdx.x;
  const int b = blockIdx.x;
  const int beg = bucket_offs[b], end = bucket_offs[b + 1];
  const int len = end - beg;
  const bool useLds = (len <= LDSCAP);

  cnt[t] = 0;
  __syncthreads();

  if (useLds) {
    for (int k = t; k < len; k += 256) {
      int2 e = bpart[beg + k];
      ebuf[k] = e;
      atomicAdd(&cnt[e.x >> 20], 1);
    }
  } else {
    for (int k = beg + t; k < end; k += 256)
      atomicAdd(&cnt[bpart[k].x >> 20], 1);
  }
  __syncthreads();

  int v = cnt[t], s = v;
#pragma unroll
  for (int d = 1; d < 64; d <<= 1) {
    int u = __shfl_up(s, d, 64);
    if ((t & 63) >= d) s += u;
  }
  if ((t & 63) == 63) wtot[t >> 6] = s;
  __syncthreads();
  int base = 0;
  const int wv_ = t >> 6;
  if (wv_ > 0) base += wtot[0];
  if (wv_ > 1) base += wtot[1];
  if (wv_ > 2) base += wtot[2];
  const int g = beg + base + s - v;  // global exclusive offset for node t
  cur[t] = g;
  const int node = (b << SHIFT) + t;
  if (node < N) noffs[node] = g;
  if (b == NB - 1 && t == 0) noffs[N] = E;
  __syncthreads();

  if (useLds) {
    for (int k = t; k < len; k += 256) {
      int2 e = ebuf[k];
      int pos = atomicAdd(&cur[e.x >> 20], 1);
      csr[pos] = make_int2(e.x & SRCMASK, e.y);
    }
  } else {
    for (int k = beg + t; k < end; k += 256) {
      int2 e = bpart[k];
      int pos = atomicAdd(&cur[e.x >> 20], 1);
      csr[pos] = make_int2(e.x & SRCMASK, e.y);
    }
  }
}

// ---------------- Fused: h3[n] = relu(sum_e w*h1[src_e]) . W2 + b2 ----------------
// R13 structure + R21 f32x2 accumulators (measured neutral, kept).
__global__ __launch_bounds__(256) void spmm1_fused_kernel(
    const int* __restrict__ noffs, const int2* __restrict__ csr,
    const unsigned short* __restrict__ h1, const float* __restrict__ W2,
    const float* __restrict__ b2, float* __restrict__ h3, int N) {
  int wave = (blockIdx.x * 256 + threadIdx.x) >> 6;
  int lane = threadIdx.x & 63;
  if (wave >= N) return;
  int beg = noffs[wave], end = noffs[wave + 1];
  const int e8 = lane >> 3;        // eighth 0..7 (edge subset)
  const int l8 = lane & 7;         // dim group: dims 8*l8 .. 8*l8+7

  f32x2 a01 = {0.f, 0.f}, a23 = {0.f, 0.f};
  f32x2 a45 = {0.f, 0.f}, a67 = {0.f, 0.f};
  int k = beg + e8;

  int2 eA, eB;
  if (k + 8 < end) { eA = csr[k]; eB = csr[k + 8]; }
  while (k + 8 < end) {
    uint4 vA = *reinterpret_cast<const uint4*>(h1 + (long)eA.x * HID + 8 * l8);
    uint4 vB = *reinterpret_cast<const uint4*>(h1 + (long)eB.x * HID + 8 * l8);
    float wA = __int_as_float(eA.y), wB = __int_as_float(eB.y);
    int kn = k + 16;
    if (kn + 8 < end) { eA = csr[kn]; eB = csr[kn + 8]; }  // prefetch next pair
    f32x2 wA2 = {wA, wA}, wB2 = {wB, wB};
    a01 += wA2 * unpk2(vA.x);
    a23 += wA2 * unpk2(vA.y);
    a45 += wA2 * unpk2(vA.z);
    a67 += wA2 * unpk2(vA.w);
    a01 += wB2 * unpk2(vB.x);
    a23 += wB2 * unpk2(vB.y);
    a45 += wB2 * unpk2(vB.z);
    a67 += wB2 * unpk2(vB.w);
    k = kn;
  }
  for (; k < end; k += 8) {
    int2 e = csr[k];
    uint4 v = *reinterpret_cast<const uint4*>(h1 + (long)e.x * HID + 8 * l8);
    float w = __int_as_float(e.y);
    f32x2 w2v = {w, w};
    a01 += w2v * unpk2(v.x);
    a23 += w2v * unpk2(v.y);
    a45 += w2v * unpk2(v.z);
    a67 += w2v * unpk2(v.w);
  }

  float a0 = a01[0], a1 = a01[1], a2 = a23[0], a3 = a23[1];
  float a4 = a45[0], a5 = a45[1], a6 = a67[0], a7 = a67[1];

  {
    const bool hi = (e8 & 1);
    float s0 = hi ? a0 : a4;  float r0 = __shfl_xor(s0, 8, 64);
    float s1 = hi ? a1 : a5;  float r1 = __shfl_xor(s1, 8, 64);
    float s2 = hi ? a2 : a6;  float r2 = __shfl_xor(s2, 8, 64);
    float s3 = hi ? a3 : a7;  float r3 = __shfl_xor(s3, 8, 64);
    a0 = (hi ? a4 : a0) + r0;
    a1 = (hi ? a5 : a1) + r1;
    a2 = (hi ? a6 : a2) + r2;
    a3 = (hi ? a7 : a3) + r3;
  }
  {
    const bool hi = (e8 >> 1) & 1;
    float s0 = hi ? a0 : a2;  float r0 = __shfl_xor(s0, 16, 64);
    float s1 = hi ? a1 : a3;  float r1 = __shfl_xor(s1, 16, 64);
    a0 = (hi ? a2 : a0) + r0;
    a1 = (hi ? a3 : a1) + r1;
  }
  {
    const bool hi = (e8 >> 2) & 1;
    float s0 = hi ? a0 : a1;  float r0 = __shfl_xor(s0, 32, 64);
    a0 = (hi ? a1 : a0) + r0;
  }
  const int dim = 8 * l8 + 4 * (e8 & 1) + 2 * ((e8 >> 1) & 1) + ((e8 >> 2) & 1);
  float s = fmaxf(a0, 0.f) * W2[dim];
  s += __shfl_xor(s, 1, 64);
  s += __shfl_xor(s, 2, 64);
  s += __shfl_xor(s, 4, 64);
  s += __shfl_xor(s, 8, 64);
  s += __shfl_xor(s, 16, 64);
  s += __shfl_xor(s, 32, 64);
  if (lane == 0) h3[wave] = s + b2[0];
}

// ---------------- Gather spmm2: out[n] = sum_e w*h3[src_e] ----------------
__global__ __launch_bounds__(256) void spmm2_gather_kernel(
    const int* __restrict__ noffs, const int2* __restrict__ csr,
    const float* __restrict__ h3, float* __restrict__ out, int N) {
  int n = blockIdx.x * 256 + threadIdx.x;
  if (n >= N) return;
  int beg = noffs[n], end = noffs[n + 1];
  float acc = 0.f;
  int k = beg;
  if (k < end && (k & 1)) {                       // align to int4
    int2 e = csr[k];
    acc += __int_as_float(e.y) * h3[e.x];
    ++k;
  }
  for (; k + 1 < end; k += 2) {
    int4 e2 = *reinterpret_cast<const int4*>(&csr[k]);
    acc += __int_as_float(e2.y) * h3[e2.x];
    acc += __int_as_float(e2.w) * h3[e2.z];
  }
  if (k < end) {
    int2 e = csr[k];
    acc += __int_as_float(e.y) * h3[e.x];
  }
  out[n] = acc;
}

extern "C" void kernel_launch(void* const* d_in, const int* in_sizes, int n_in,
                              void* d_out, int out_size, void* d_ws, size_t ws_size,
                              hipStream_t stream) {
  const float* x    = (const float*)d_in[0];
  const int*   esrc = (const int*)d_in[1];
  const int*   edst = (const int*)d_in[2];
  const float* ew   = (const float*)d_in[3];
  const float* W1   = (const float*)d_in[4];
  const float* b1   = (const float*)d_in[5];
  const float* W2   = (const float*)d_in[6];
  const float* b2   = (const float*)d_in[7];
  float* out = (float*)d_out;

  const int N = in_sizes[0] / IN_DIM;
  const int E = in_sizes[1];
  const int NB = (N + BNODES - 1) >> SHIFT;         // 391 @ N=100k
  const int NCH = (E + CH - 1) / CH;                // 782 @ E=1.6M

  char* p = (char*)d_ws;
  auto alloc = [&](size_t bytes) {
    char* r = p;
    p += (bytes + 15) & ~(size_t)15;
    return r;
  };
  unsigned short* h1 = (unsigned short*)alloc((size_t)N * HID * sizeof(unsigned short));
  unsigned short* W1b= (unsigned short*)alloc((size_t)8192 * sizeof(unsigned short));
  float* h3          = (float*)alloc((size_t)N * sizeof(float));
  int*   bucket_size = (int*)alloc((size_t)NB * sizeof(int));
  int*   bucket_offs = (int*)alloc((size_t)(NB + 1) * sizeof(int));
  int*   noffs       = (int*)alloc((size_t)(N + 1) * sizeof(int));
  int*   blockRel    = (int*)alloc((size_t)NCH * NB * sizeof(int));
  int2*  bpart       = (int2*)alloc((size_t)E * sizeof(int2));
  int2*  csr         = (int2*)alloc((size_t)E * sizeof(int2));

  w1pack_kernel<<<32, 256, 0, stream>>>(W1, W1b, bucket_size, NB);
  gemm1_kernel<<<(N + 63) / 64, 256, 0, stream>>>(x, W1b, b1, h1, N);

  bucket_count_kernel<<<NCH, 256, 0, stream>>>(edst, bucket_size, blockRel, NB, E, NCH);
  bucket_scan_kernel<<<1, 1024, 0, stream>>>(bucket_size, bucket_offs, NB);
  bucket_place_kernel<<<NCH, 256, 0, stream>>>(esrc, edst, ew, bucket_offs,
                                               blockRel, bpart, NB, E, NCH);
  csr_place_kernel<<<NB, 256, 0, stream>>>(bpart, bucket_offs, csr, noffs, N, NB, E);

  spmm1_fused_kernel<<<(unsigned)(((long)N * 64 + 255) / 256), 256, 0, stream>>>(
      noffs, csr, h1, W2, b2, h3, N);

  spmm2_gather_kernel<<<(N + 255) / 256, 256, 0, stream>>>(noffs, csr, h3, out, N);
}

// Round 23
// 121.091 us; speedup vs baseline: 1.0919x; 1.0919x over previous
//
#include <hip/hip_runtime.h>

#define IN_DIM 128
#define HID 64
#define SHIFT 8                 // 256 nodes per bucket
#define BNODES 256
#define NBMAX 1024              // NB=391 @ N=100k
#define CH 4096                 // edges per chunk (measured optimum: 2048 ✗, 4096 ✓, 32768 ✗✗)
#define SRCMASK 0xFFFFF         // src packed in low 20 bits (N <= 1M)
#define LDSCAP 6144             // csr_place LDS edge-staging capacity (48 KB)
#define XSTR 130                // Xs row stride in shorts

using bf16x8 = __attribute__((ext_vector_type(8))) short;   // 8 bf16 (4 VGPRs)
using f32x4  = __attribute__((ext_vector_type(4))) float;
using f32x2  = __attribute__((ext_vector_type(2))) float;

// bf16 round-to-nearest-even
__device__ inline unsigned short f2bf(float f) {
  unsigned u = __float_as_uint(f);
  u += 0x7FFF + ((u >> 16) & 1);
  return (unsigned short)(u >> 16);
}
__device__ inline float bf2f_lo(unsigned v) {   // low bf16 of a packed u32
  return __uint_as_float(v << 16);
}
__device__ inline float bf2f_hi(unsigned v) {   // high bf16 of a packed u32
  return __uint_as_float(v & 0xFFFF0000u);
}
__device__ inline f32x2 unpk2(unsigned v) {     // {lo, hi} as f32 pair
  return (f32x2){bf2f_lo(v), bf2f_hi(v)};
}

// R18: bijective XCD-aware block->chunk remap (kept).
__device__ inline int xcd_chunk(int bid, int nch) {
  int q = nch >> 3, r = nch & 7;
  int xcd = bid & 7, idx = bid >> 3;
  return (xcd < r) ? xcd * (q + 1) + idx : r * (q + 1) + (xcd - r) * q + idx;
}

// ---------------- Prep: pack W1 into MFMA B-fragment order + zero counters ----------------
__global__ __launch_bounds__(256) void w1pack_kernel(
    const float* __restrict__ W1, unsigned short* __restrict__ W1b,
    int* __restrict__ bucket_size, int NB) {
  if (blockIdx.x == 0) {
    for (int i = threadIdx.x; i < NB; i += 256) bucket_size[i] = 0;
  }
  int idx = blockIdx.x * 256 + threadIdx.x;   // 8192 total
  if (idx >= 4 * 4 * 64 * 8) return;
  int i    = idx & 7;
  int lane = (idx >> 3) & 63;
  int kc   = (idx >> 9) & 3;
  int jt   = idx >> 11;
  int k = kc * 32 + ((lane >> 4) << 3) + i;
  int n = jt * 16 + (lane & 15);
  W1b[idx] = f2bf(W1[k * HID + n]);
}

// ---------------- Kernel 1: h1 = bf16(x @ W1 + b1) via MFMA ----------------
// R17/R20 structure (proven): coalesced per-wave LDS staging of x, A-frags
// via ds_read_b128, B-frags from pre-packed W1b (L1-resident, uint4/lane).
__global__ __launch_bounds__(256) void gemm1_kernel(
    const float* __restrict__ x, const unsigned short* __restrict__ W1b,
    const float* __restrict__ b1, unsigned short* __restrict__ h1, int N) {
  __shared__ unsigned short Xs[4][16][XSTR];   // 16.6 KB
  const int lane = threadIdx.x & 63;
  const int w    = threadIdx.x >> 6;           // wave id: rows 16w..16w+15
  const int rblk = blockIdx.x * 64;

  for (int it = 0; it < 8; ++it) {
    int flat = it * 64 + lane;                 // 0..511
    int row  = flat >> 5;                      // 32 float4 per row
    int c4   = (flat & 31) * 4;
    int gr = rblk + w * 16 + row;
    if (gr > N - 1) gr = N - 1;
    float4 v = *reinterpret_cast<const float4*>(x + (long)gr * IN_DIM + c4);
    ushort4 o;
    o.x = f2bf(v.x); o.y = f2bf(v.y); o.z = f2bf(v.z); o.w = f2bf(v.w);
    *reinterpret_cast<ushort4*>(&Xs[w][row][c4]) = o;
  }
  __syncthreads();

  bf16x8 a[4];
#pragma unroll
  for (int kc = 0; kc < 4; ++kc) {
    a[kc] = *reinterpret_cast<const bf16x8*>(
        &Xs[w][lane & 15][kc * 32 + ((lane >> 4) << 3)]);
  }

  const uint4* wb = reinterpret_cast<const uint4*>(W1b);
#pragma unroll
  for (int jt = 0; jt < 4; ++jt) {
    f32x4 acc = {0.f, 0.f, 0.f, 0.f};
#pragma unroll
    for (int kc = 0; kc < 4; ++kc) {
      union { uint4 q; bf16x8 v; } bu;
      bu.q = wb[(jt * 4 + kc) * 64 + lane];
      acc = __builtin_amdgcn_mfma_f32_16x16x32_bf16(a[kc], bu.v, acc, 0, 0, 0);
    }
    const int col = jt * 16 + (lane & 15);
    const float bb = b1[col];
#pragma unroll
    for (int r = 0; r < 4; ++r) {
      int row = (lane >> 4) * 4 + r;
      int gr = rblk + w * 16 + row;
      if (gr < N) h1[(long)gr * HID + col] = f2bf(acc[r] + bb);
    }
  }
}

// ------------- Bucket partition pass 1: per-chunk histogram + reservation -------------
__global__ __launch_bounds__(256) void bucket_count_kernel(
    const int* __restrict__ dst, int* __restrict__ bucket_size,
    int* __restrict__ blockRel, int NB, int E, int NCH) {
  __shared__ int hist[NBMAX];
  const int c = xcd_chunk(blockIdx.x, NCH);
  for (int i = threadIdx.x; i < NB; i += 256) hist[i] = 0;
  __syncthreads();
  int base = c * CH;
  int end = min(base + CH, E);
  for (int k = base + threadIdx.x * 4; k + 3 < end; k += 1024) {
    int4 d4 = *reinterpret_cast<const int4*>(&dst[k]);
    atomicAdd(&hist[d4.x >> SHIFT], 1);
    atomicAdd(&hist[d4.y >> SHIFT], 1);
    atomicAdd(&hist[d4.z >> SHIFT], 1);
    atomicAdd(&hist[d4.w >> SHIFT], 1);
  }
  int tail_start = base + ((end - base) & ~3);
  for (int k = tail_start + threadIdx.x; k < end; k += 256)
    atomicAdd(&hist[dst[k] >> SHIFT], 1);
  __syncthreads();
  for (int i = threadIdx.x; i < NB; i += 256) {
    int cv = hist[i];
    int r = cv ? atomicAdd(&bucket_size[i], cv) : 0;
    blockRel[(long)c * NB + i] = r;
  }
}

// ------------- Pass 2: exclusive scan of bucket sizes (single block) -------------
__global__ __launch_bounds__(1024) void bucket_scan_kernel(
    const int* __restrict__ bucket_size, int* __restrict__ bucket_offs, int NB) {
  __shared__ int tmp[1024];
  int tid = threadIdx.x;
  int v = (tid < NB) ? bucket_size[tid] : 0;
  tmp[tid] = v;
  __syncthreads();
  for (int off = 1; off < 1024; off <<= 1) {
    int t = (tid >= off) ? tmp[tid - off] : 0;
    __syncthreads();
    tmp[tid] += t;
    __syncthreads();
  }
  if (tid <= NB) bucket_offs[tid] = tmp[tid] - v;  // exclusive; offs[NB]=E
}

// ------------- Pass 3: place edges into bucket-partitioned array -------------
__global__ __launch_bounds__(256) void bucket_place_kernel(
    const int* __restrict__ src, const int* __restrict__ dst,
    const float* __restrict__ w, const int* __restrict__ bucket_offs,
    const int* __restrict__ blockRel, int2* __restrict__ bpart,
    int NB, int E, int NCH) {
  __shared__ int cur[NBMAX];
  const int c = xcd_chunk(blockIdx.x, NCH);
  for (int i = threadIdx.x; i < NB; i += 256)
    cur[i] = bucket_offs[i] + blockRel[(long)c * NB + i];
  __syncthreads();
  int base = c * CH;
  int end = min(base + CH, E);
  for (int k = base + threadIdx.x * 4; k + 3 < end; k += 1024) {
    int4   s4 = *reinterpret_cast<const int4*>(&src[k]);
    int4   d4 = *reinterpret_cast<const int4*>(&dst[k]);
    float4 w4 = *reinterpret_cast<const float4*>(&w[k]);
    int p0 = atomicAdd(&cur[d4.x >> SHIFT], 1);
    int p1 = atomicAdd(&cur[d4.y >> SHIFT], 1);
    int p2 = atomicAdd(&cur[d4.z >> SHIFT], 1);
    int p3 = atomicAdd(&cur[d4.w >> SHIFT], 1);
    bpart[p0] = make_int2((s4.x & SRCMASK) | ((d4.x & (BNODES - 1)) << 20),
                          __float_as_int(w4.x));
    bpart[p1] = make_int2((s4.y & SRCMASK) | ((d4.y & (BNODES - 1)) << 20),
                          __float_as_int(w4.y));
    bpart[p2] = make_int2((s4.z & SRCMASK) | ((d4.z & (BNODES - 1)) << 20),
                          __float_as_int(w4.z));
    bpart[p3] = make_int2((s4.w & SRCMASK) | ((d4.w & (BNODES - 1)) << 20),
                          __float_as_int(w4.w));
  }
  int tail_start = base + ((end - base) & ~3);
  for (int k = tail_start + threadIdx.x; k < end; k += 256) {
    int d = dst[k];
    int b = d >> SHIFT;
    int pos = atomicAdd(&cur[b], 1);
    bpart[pos] = make_int2((src[k] & SRCMASK) | ((d & (BNODES - 1)) << 20),
                           __float_as_int(w[k]));
  }
}

// ------------- Pass 4: per-bucket CSR finalize (LDS-staged) -------------
__global__ __launch_bounds__(256) void csr_place_kernel(
    const int2* __restrict__ bpart, const int* __restrict__ bucket_offs,
    int2* __restrict__ csr, int* __restrict__ noffs, int N, int NB, int E) {
  __shared__ int cnt[BNODES];
  __shared__ int cur[BNODES];
  __shared__ int wtot[4];
  __shared__ int2 ebuf[LDSCAP];
  const int t = threadIdx.x;
  const int b = blockIdx.x;
  const int beg = bucket_offs[b], end = bucket_offs[b + 1];
  const int len = end - beg;
  const bool useLds = (len <= LDSCAP);

  cnt[t] = 0;
  __syncthreads();

  if (useLds) {
    for (int k = t; k < len; k += 256) {
      int2 e = bpart[beg + k];
      ebuf[k] = e;
      atomicAdd(&cnt[e.x >> 20], 1);
    }
  } else {
    for (int k = beg + t; k < end; k += 256)
      atomicAdd(&cnt[bpart[k].x >> 20], 1);
  }
  __syncthreads();

  int v = cnt[t], s = v;
#pragma unroll
  for (int d = 1; d < 64; d <<= 1) {
    int u = __shfl_up(s, d, 64);
    if ((t & 63) >= d) s += u;
  }
  if ((t & 63) == 63) wtot[t >> 6] = s;
  __syncthreads();
  int base = 0;
  const int wv_ = t >> 6;
  if (wv_ > 0) base += wtot[0];
  if (wv_ > 1) base += wtot[1];
  if (wv_ > 2) base += wtot[2];
  const int g = beg + base + s - v;  // global exclusive offset for node t
  cur[t] = g;
  const int node = (b << SHIFT) + t;
  if (node < N) noffs[node] = g;
  if (b == NB - 1 && t == 0) noffs[N] = E;
  __syncthreads();

  if (useLds) {
    for (int k = t; k < len; k += 256) {
      int2 e = ebuf[k];
      int pos = atomicAdd(&cur[e.x >> 20], 1);
      csr[pos] = make_int2(e.x & SRCMASK, e.y);
    }
  } else {
    for (int k = beg + t; k < end; k += 256) {
      int2 e = bpart[k];
      int pos = atomicAdd(&cur[e.x >> 20], 1);
      csr[pos] = make_int2(e.x & SRCMASK, e.y);
    }
  }
}

// ---------------- Fused: h3[n] = relu(sum_e w*h1[src_e]) . W2 + b2 ----------------
// R13 structure + R21 f32x2 accumulators (neutral, kept).
__global__ __launch_bounds__(256) void spmm1_fused_kernel(
    const int* __restrict__ noffs, const int2* __restrict__ csr,
    const unsigned short* __restrict__ h1, const float* __restrict__ W2,
    const float* __restrict__ b2, float* __restrict__ h3, int N) {
  int wave = (blockIdx.x * 256 + threadIdx.x) >> 6;
  int lane = threadIdx.x & 63;
  if (wave >= N) return;
  int beg = noffs[wave], end = noffs[wave + 1];
  const int e8 = lane >> 3;        // eighth 0..7 (edge subset)
  const int l8 = lane & 7;         // dim group: dims 8*l8 .. 8*l8+7

  f32x2 a01 = {0.f, 0.f}, a23 = {0.f, 0.f};
  f32x2 a45 = {0.f, 0.f}, a67 = {0.f, 0.f};
  int k = beg + e8;

  int2 eA, eB;
  if (k + 8 < end) { eA = csr[k]; eB = csr[k + 8]; }
  while (k + 8 < end) {
    uint4 vA = *reinterpret_cast<const uint4*>(h1 + (long)eA.x * HID + 8 * l8);
    uint4 vB = *reinterpret_cast<const uint4*>(h1 + (long)eB.x * HID + 8 * l8);
    float wA = __int_as_float(eA.y), wB = __int_as_float(eB.y);
    int kn = k + 16;
    if (kn + 8 < end) { eA = csr[kn]; eB = csr[kn + 8]; }  // prefetch next pair
    f32x2 wA2 = {wA, wA}, wB2 = {wB, wB};
    a01 += wA2 * unpk2(vA.x);
    a23 += wA2 * unpk2(vA.y);
    a45 += wA2 * unpk2(vA.z);
    a67 += wA2 * unpk2(vA.w);
    a01 += wB2 * unpk2(vB.x);
    a23 += wB2 * unpk2(vB.y);
    a45 += wB2 * unpk2(vB.z);
    a67 += wB2 * unpk2(vB.w);
    k = kn;
  }
  for (; k < end; k += 8) {
    int2 e = csr[k];
    uint4 v = *reinterpret_cast<const uint4*>(h1 + (long)e.x * HID + 8 * l8);
    float w = __int_as_float(e.y);
    f32x2 w2v = {w, w};
    a01 += w2v * unpk2(v.x);
    a23 += w2v * unpk2(v.y);
    a45 += w2v * unpk2(v.z);
    a67 += w2v * unpk2(v.w);
  }

  float a0 = a01[0], a1 = a01[1], a2 = a23[0], a3 = a23[1];
  float a4 = a45[0], a5 = a45[1], a6 = a67[0], a7 = a67[1];

  {
    const bool hi = (e8 & 1);
    float s0 = hi ? a0 : a4;  float r0 = __shfl_xor(s0, 8, 64);
    float s1 = hi ? a1 : a5;  float r1 = __shfl_xor(s1, 8, 64);
    float s2 = hi ? a2 : a6;  float r2 = __shfl_xor(s2, 8, 64);
    float s3 = hi ? a3 : a7;  float r3 = __shfl_xor(s3, 8, 64);
    a0 = (hi ? a4 : a0) + r0;
    a1 = (hi ? a5 : a1) + r1;
    a2 = (hi ? a6 : a2) + r2;
    a3 = (hi ? a7 : a3) + r3;
  }
  {
    const bool hi = (e8 >> 1) & 1;
    float s0 = hi ? a0 : a2;  float r0 = __shfl_xor(s0, 16, 64);
    float s1 = hi ? a1 : a3;  float r1 = __shfl_xor(s1, 16, 64);
    a0 = (hi ? a2 : a0) + r0;
    a1 = (hi ? a3 : a1) + r1;
  }
  {
    const bool hi = (e8 >> 2) & 1;
    float s0 = hi ? a0 : a1;  float r0 = __shfl_xor(s0, 32, 64);
    a0 = (hi ? a1 : a0) + r0;
  }
  const int dim = 8 * l8 + 4 * (e8 & 1) + 2 * ((e8 >> 1) & 1) + ((e8 >> 2) & 1);
  float s = fmaxf(a0, 0.f) * W2[dim];
  s += __shfl_xor(s, 1, 64);
  s += __shfl_xor(s, 2, 64);
  s += __shfl_xor(s, 4, 64);
  s += __shfl_xor(s, 8, 64);
  s += __shfl_xor(s, 16, 64);
  s += __shfl_xor(s, 32, 64);
  if (lane == 0) h3[wave] = s + b2[0];
}

// ---------------- Gather spmm2: out[n] = sum_e w*h3[src_e] ----------------
__global__ __launch_bounds__(256) void spmm2_gather_kernel(
    const int* __restrict__ noffs, const int2* __restrict__ csr,
    const float* __restrict__ h3, float* __restrict__ out, int N) {
  int n = blockIdx.x * 256 + threadIdx.x;
  if (n >= N) return;
  int beg = noffs[n], end = noffs[n + 1];
  float acc = 0.f;
  int k = beg;
  if (k < end && (k & 1)) {                       // align to int4
    int2 e = csr[k];
    acc += __int_as_float(e.y) * h3[e.x];
    ++k;
  }
  for (; k + 1 < end; k += 2) {
    int4 e2 = *reinterpret_cast<const int4*>(&csr[k]);
    acc += __int_as_float(e2.y) * h3[e2.x];
    acc += __int_as_float(e2.w) * h3[e2.z];
  }
  if (k < end) {
    int2 e = csr[k];
    acc += __int_as_float(e.y) * h3[e.x];
  }
  out[n] = acc;
}

extern "C" void kernel_launch(void* const* d_in, const int* in_sizes, int n_in,
                              void* d_out, int out_size, void* d_ws, size_t ws_size,
                              hipStream_t stream) {
  const float* x    = (const float*)d_in[0];
  const int*   esrc = (const int*)d_in[1];
  const int*   edst = (const int*)d_in[2];
  const float* ew   = (const float*)d_in[3];
  const float* W1   = (const float*)d_in[4];
  const float* b1   = (const float*)d_in[5];
  const float* W2   = (const float*)d_in[6];
  const float* b2   = (const float*)d_in[7];
  float* out = (float*)d_out;

  const int N = in_sizes[0] / IN_DIM;
  const int E = in_sizes[1];
  const int NB = (N + BNODES - 1) >> SHIFT;         // 391 @ N=100k
  const int NCH = (E + CH - 1) / CH;                // 391 @ E=1.6M

  char* p = (char*)d_ws;
  auto alloc = [&](size_t bytes) {
    char* r = p;
    p += (bytes + 15) & ~(size_t)15;
    return r;
  };
  unsigned short* h1 = (unsigned short*)alloc((size_t)N * HID * sizeof(unsigned short));
  unsigned short* W1b= (unsigned short*)alloc((size_t)8192 * sizeof(unsigned short));
  float* h3          = (float*)alloc((size_t)N * sizeof(float));
  int*   bucket_size = (int*)alloc((size_t)NB * sizeof(int));
  int*   bucket_offs = (int*)alloc((size_t)(NB + 1) * sizeof(int));
  int*   noffs       = (int*)alloc((size_t)(N + 1) * sizeof(int));
  int*   blockRel    = (int*)alloc((size_t)NCH * NB * sizeof(int));
  int2*  bpart       = (int2*)alloc((size_t)E * sizeof(int2));
  int2*  csr         = (int2*)alloc((size_t)E * sizeof(int2));

  w1pack_kernel<<<32, 256, 0, stream>>>(W1, W1b, bucket_size, NB);
  gemm1_kernel<<<(N + 63) / 64, 256, 0, stream>>>(x, W1b, b1, h1, N);

  bucket_count_kernel<<<NCH, 256, 0, stream>>>(edst, bucket_size, blockRel, NB, E, NCH);
  bucket_scan_kernel<<<1, 1024, 0, stream>>>(bucket_size, bucket_offs, NB);
  bucket_place_kernel<<<NCH, 256, 0, stream>>>(esrc, edst, ew, bucket_offs,
                                               blockRel, bpart, NB, E, NCH);
  csr_place_kernel<<<NB, 256, 0, stream>>>(bpart, bucket_offs, csr, noffs, N, NB, E);

  spmm1_fused_kernel<<<(unsigned)(((long)N * 64 + 255) / 256), 256, 0, stream>>>(
      noffs, csr, h1, W2, b2, h3, N);

  spmm2_gather_kernel<<<(N + 255) / 256, 256, 0, stream>>>(noffs, csr, h3, out, N);
}

// Round 24
// 116.275 us; speedup vs baseline: 1.1371x; 1.0414x over previous
//
#include <hip/hip_runtime.h>

#define IN_DIM 128
#define HID 64
#define SHIFT 8                 // 256 nodes per bucket
#define BNODES 256
#define NBMAX 1024              // NB=391 @ N=100k
#define CH 4096                 // edges per chunk (measured optimum: 2048 ✗, 4096 ✓, 32768 ✗✗)
#define SRCMASK 0xFFFFF         // src packed in low 20 bits (N <= 1M)
#define LDSCAP 6144             // csr_place LDS edge-staging capacity (48 KB)
#define XSTR 130                // Xs row stride in shorts

using bf16x8 = __attribute__((ext_vector_type(8))) short;   // 8 bf16 (4 VGPRs)
using f32x4  = __attribute__((ext_vector_type(4))) float;
using f32x2  = __attribute__((ext_vector_type(2))) float;

// bf16 round-to-nearest-even
__device__ inline unsigned short f2bf(float f) {
  unsigned u = __float_as_uint(f);
  u += 0x7FFF + ((u >> 16) & 1);
  return (unsigned short)(u >> 16);
}
__device__ inline float bf2f_lo(unsigned v) {   // low bf16 of a packed u32
  return __uint_as_float(v << 16);
}
__device__ inline float bf2f_hi(unsigned v) {   // high bf16 of a packed u32
  return __uint_as_float(v & 0xFFFF0000u);
}
__device__ inline f32x2 unpk2(unsigned v) {     // {lo, hi} as f32 pair
  return (f32x2){bf2f_lo(v), bf2f_hi(v)};
}

// R18: bijective XCD-aware block->chunk remap (kept).
__device__ inline int xcd_chunk(int bid, int nch) {
  int q = nch >> 3, r = nch & 7;
  int xcd = bid & 7, idx = bid >> 3;
  return (xcd < r) ? xcd * (q + 1) + idx : r * (q + 1) + (xcd - r) * q + idx;
}

// ---------------- Prep: pack W1 into MFMA B-fragment order + zero counters ----------------
__global__ __launch_bounds__(256) void w1pack_kernel(
    const float* __restrict__ W1, unsigned short* __restrict__ W1b,
    int* __restrict__ bucket_size, int NB) {
  if (blockIdx.x == 0) {
    for (int i = threadIdx.x; i < NB; i += 256) bucket_size[i] = 0;
  }
  int idx = blockIdx.x * 256 + threadIdx.x;   // 8192 total
  if (idx >= 4 * 4 * 64 * 8) return;
  int i    = idx & 7;
  int lane = (idx >> 3) & 63;
  int kc   = (idx >> 9) & 3;
  int jt   = idx >> 11;
  int k = kc * 32 + ((lane >> 4) << 3) + i;
  int n = jt * 16 + (lane & 15);
  W1b[idx] = f2bf(W1[k * HID + n]);
}

// ---------------- Kernel 1: h1 = bf16(x @ W1 + b1) via MFMA ----------------
// R17/R20 structure (proven): coalesced per-wave LDS staging of x, A-frags
// via ds_read_b128, B-frags from pre-packed W1b (L1-resident, uint4/lane).
__global__ __launch_bounds__(256) void gemm1_kernel(
    const float* __restrict__ x, const unsigned short* __restrict__ W1b,
    const float* __restrict__ b1, unsigned short* __restrict__ h1, int N) {
  __shared__ unsigned short Xs[4][16][XSTR];   // 16.6 KB
  const int lane = threadIdx.x & 63;
  const int w    = threadIdx.x >> 6;           // wave id: rows 16w..16w+15
  const int rblk = blockIdx.x * 64;

  for (int it = 0; it < 8; ++it) {
    int flat = it * 64 + lane;                 // 0..511
    int row  = flat >> 5;                      // 32 float4 per row
    int c4   = (flat & 31) * 4;
    int gr = rblk + w * 16 + row;
    if (gr > N - 1) gr = N - 1;
    float4 v = *reinterpret_cast<const float4*>(x + (long)gr * IN_DIM + c4);
    ushort4 o;
    o.x = f2bf(v.x); o.y = f2bf(v.y); o.z = f2bf(v.z); o.w = f2bf(v.w);
    *reinterpret_cast<ushort4*>(&Xs[w][row][c4]) = o;
  }
  __syncthreads();

  bf16x8 a[4];
#pragma unroll
  for (int kc = 0; kc < 4; ++kc) {
    a[kc] = *reinterpret_cast<const bf16x8*>(
        &Xs[w][lane & 15][kc * 32 + ((lane >> 4) << 3)]);
  }

  const uint4* wb = reinterpret_cast<const uint4*>(W1b);
#pragma unroll
  for (int jt = 0; jt < 4; ++jt) {
    f32x4 acc = {0.f, 0.f, 0.f, 0.f};
#pragma unroll
    for (int kc = 0; kc < 4; ++kc) {
      union { uint4 q; bf16x8 v; } bu;
      bu.q = wb[(jt * 4 + kc) * 64 + lane];
      acc = __builtin_amdgcn_mfma_f32_16x16x32_bf16(a[kc], bu.v, acc, 0, 0, 0);
    }
    const int col = jt * 16 + (lane & 15);
    const float bb = b1[col];
#pragma unroll
    for (int r = 0; r < 4; ++r) {
      int row = (lane >> 4) * 4 + r;
      int gr = rblk + w * 16 + row;
      if (gr < N) h1[(long)gr * HID + col] = f2bf(acc[r] + bb);
    }
  }
}

// ------------- Bucket partition pass 1: per-chunk histogram + reservation -------------
// R24: 512 threads (391 blocks were 1.5/CU = TLP-starved; doubles resident waves).
__global__ __launch_bounds__(512) void bucket_count_kernel(
    const int* __restrict__ dst, int* __restrict__ bucket_size,
    int* __restrict__ blockRel, int NB, int E, int NCH) {
  __shared__ int hist[NBMAX];
  const int c = xcd_chunk(blockIdx.x, NCH);
  for (int i = threadIdx.x; i < NB; i += 512) hist[i] = 0;
  __syncthreads();
  int base = c * CH;
  int end = min(base + CH, E);
  for (int k = base + threadIdx.x * 4; k + 3 < end; k += 2048) {
    int4 d4 = *reinterpret_cast<const int4*>(&dst[k]);
    atomicAdd(&hist[d4.x >> SHIFT], 1);
    atomicAdd(&hist[d4.y >> SHIFT], 1);
    atomicAdd(&hist[d4.z >> SHIFT], 1);
    atomicAdd(&hist[d4.w >> SHIFT], 1);
  }
  int tail_start = base + ((end - base) & ~3);
  for (int k = tail_start + threadIdx.x; k < end; k += 512)
    atomicAdd(&hist[dst[k] >> SHIFT], 1);
  __syncthreads();
  for (int i = threadIdx.x; i < NB; i += 512) {
    int cv = hist[i];
    int r = cv ? atomicAdd(&bucket_size[i], cv) : 0;
    blockRel[(long)c * NB + i] = r;
  }
}

// ------------- Pass 2: exclusive scan of bucket sizes (single block) -------------
__global__ __launch_bounds__(1024) void bucket_scan_kernel(
    const int* __restrict__ bucket_size, int* __restrict__ bucket_offs, int NB) {
  __shared__ int tmp[1024];
  int tid = threadIdx.x;
  int v = (tid < NB) ? bucket_size[tid] : 0;
  tmp[tid] = v;
  __syncthreads();
  for (int off = 1; off < 1024; off <<= 1) {
    int t = (tid >= off) ? tmp[tid - off] : 0;
    __syncthreads();
    tmp[tid] += t;
    __syncthreads();
  }
  if (tid <= NB) bucket_offs[tid] = tmp[tid] - v;  // exclusive; offs[NB]=E
}

// ------------- Pass 3: place edges into bucket-partitioned array -------------
// R24: 512 threads (TLP).
__global__ __launch_bounds__(512) void bucket_place_kernel(
    const int* __restrict__ src, const int* __restrict__ dst,
    const float* __restrict__ w, const int* __restrict__ bucket_offs,
    const int* __restrict__ blockRel, int2* __restrict__ bpart,
    int NB, int E, int NCH) {
  __shared__ int cur[NBMAX];
  const int c = xcd_chunk(blockIdx.x, NCH);
  for (int i = threadIdx.x; i < NB; i += 512)
    cur[i] = bucket_offs[i] + blockRel[(long)c * NB + i];
  __syncthreads();
  int base = c * CH;
  int end = min(base + CH, E);
  for (int k = base + threadIdx.x * 4; k + 3 < end; k += 2048) {
    int4   s4 = *reinterpret_cast<const int4*>(&src[k]);
    int4   d4 = *reinterpret_cast<const int4*>(&dst[k]);
    float4 w4 = *reinterpret_cast<const float4*>(&w[k]);
    int p0 = atomicAdd(&cur[d4.x >> SHIFT], 1);
    int p1 = atomicAdd(&cur[d4.y >> SHIFT], 1);
    int p2 = atomicAdd(&cur[d4.z >> SHIFT], 1);
    int p3 = atomicAdd(&cur[d4.w >> SHIFT], 1);
    bpart[p0] = make_int2((s4.x & SRCMASK) | ((d4.x & (BNODES - 1)) << 20),
                          __float_as_int(w4.x));
    bpart[p1] = make_int2((s4.y & SRCMASK) | ((d4.y & (BNODES - 1)) << 20),
                          __float_as_int(w4.y));
    bpart[p2] = make_int2((s4.z & SRCMASK) | ((d4.z & (BNODES - 1)) << 20),
                          __float_as_int(w4.z));
    bpart[p3] = make_int2((s4.w & SRCMASK) | ((d4.w & (BNODES - 1)) << 20),
                          __float_as_int(w4.w));
  }
  int tail_start = base + ((end - base) & ~3);
  for (int k = tail_start + threadIdx.x; k < end; k += 512) {
    int d = dst[k];
    int b = d >> SHIFT;
    int pos = atomicAdd(&cur[b], 1);
    bpart[pos] = make_int2((src[k] & SRCMASK) | ((d & (BNODES - 1)) << 20),
                           __float_as_int(w[k]));
  }
}

// ------------- Pass 4: per-bucket CSR finalize (LDS-staged) -------------
// R24: 1024 threads (391 blocks x 4 waves was ~6 waves/CU; now 16 waves/block,
// LDS 50 KB -> 2 blocks/CU = 32 waves/CU). Scan confined to t<256 with
// uniform barriers (shfl computed by all waves; garbage in waves 4+ unused).
__global__ __launch_bounds__(1024) void csr_place_kernel(
    const int2* __restrict__ bpart, const int* __restrict__ bucket_offs,
    int2* __restrict__ csr, int* __restrict__ noffs, int N, int NB, int E) {
  __shared__ int cnt[BNODES];
  __shared__ int cur[BNODES];
  __shared__ int wtot[4];
  __shared__ int2 ebuf[LDSCAP];
  const int t = threadIdx.x;
  const int b = blockIdx.x;
  const int beg = bucket_offs[b], end = bucket_offs[b + 1];
  const int len = end - beg;
  const bool useLds = (len <= LDSCAP);

  if (t < BNODES) cnt[t] = 0;
  __syncthreads();

  if (useLds) {
    for (int k = t; k < len; k += 1024) {
      int2 e = bpart[beg + k];
      ebuf[k] = e;
      atomicAdd(&cnt[e.x >> 20], 1);
    }
  } else {
    for (int k = beg + t; k < end; k += 1024)
      atomicAdd(&cnt[bpart[k].x >> 20], 1);
  }
  __syncthreads();

  // exclusive scan of cnt[0..255]: shfl scan (waves 4+ compute unused garbage)
  int v = (t < BNODES) ? cnt[t] : 0;
  int s = v;
#pragma unroll
  for (int d = 1; d < 64; d <<= 1) {
    int u = __shfl_up(s, d, 64);
    if ((t & 63) >= d) s += u;
  }
  if (t < BNODES && (t & 63) == 63) wtot[t >> 6] = s;
  __syncthreads();
  if (t < BNODES) {
    int base = 0;
    const int wv_ = t >> 6;
    if (wv_ > 0) base += wtot[0];
    if (wv_ > 1) base += wtot[1];
    if (wv_ > 2) base += wtot[2];
    const int g = beg + base + s - v;  // global exclusive offset for node t
    cur[t] = g;
    const int node = (b << SHIFT) + t;
    if (node < N) noffs[node] = g;
  }
  if (b == NB - 1 && t == 0) noffs[N] = E;
  __syncthreads();

  if (useLds) {
    for (int k = t; k < len; k += 1024) {
      int2 e = ebuf[k];
      int pos = atomicAdd(&cur[e.x >> 20], 1);
      csr[pos] = make_int2(e.x & SRCMASK, e.y);
    }
  } else {
    for (int k = beg + t; k < end; k += 1024) {
      int2 e = bpart[k];
      int pos = atomicAdd(&cur[e.x >> 20], 1);
      csr[pos] = make_int2(e.x & SRCMASK, e.y);
    }
  }
}

// ---------------- Fused: h3[n] = relu(sum_e w*h1[src_e]) . W2 + b2 ----------------
// R13 structure + R21 f32x2. At its L2-fill roofline: FETCH 83 MB ~= 8 XCDs
// x 12.8 MB h1 (non-coherent L2s each fill h1 independently) at ~2 TB/s.
__global__ __launch_bounds__(256) void spmm1_fused_kernel(
    const int* __restrict__ noffs, const int2* __restrict__ csr,
    const unsigned short* __restrict__ h1, const float* __restrict__ W2,
    const float* __restrict__ b2, float* __restrict__ h3, int N) {
  int wave = (blockIdx.x * 256 + threadIdx.x) >> 6;
  int lane = threadIdx.x & 63;
  if (wave >= N) return;
  int beg = noffs[wave], end = noffs[wave + 1];
  const int e8 = lane >> 3;        // eighth 0..7 (edge subset)
  const int l8 = lane & 7;         // dim group: dims 8*l8 .. 8*l8+7

  f32x2 a01 = {0.f, 0.f}, a23 = {0.f, 0.f};
  f32x2 a45 = {0.f, 0.f}, a67 = {0.f, 0.f};
  int k = beg + e8;

  int2 eA, eB;
  if (k + 8 < end) { eA = csr[k]; eB = csr[k + 8]; }
  while (k + 8 < end) {
    uint4 vA = *reinterpret_cast<const uint4*>(h1 + (long)eA.x * HID + 8 * l8);
    uint4 vB = *reinterpret_cast<const uint4*>(h1 + (long)eB.x * HID + 8 * l8);
    float wA = __int_as_float(eA.y), wB = __int_as_float(eB.y);
    int kn = k + 16;
    if (kn + 8 < end) { eA = csr[kn]; eB = csr[kn + 8]; }  // prefetch next pair
    f32x2 wA2 = {wA, wA}, wB2 = {wB, wB};
    a01 += wA2 * unpk2(vA.x);
    a23 += wA2 * unpk2(vA.y);
    a45 += wA2 * unpk2(vA.z);
    a67 += wA2 * unpk2(vA.w);
    a01 += wB2 * unpk2(vB.x);
    a23 += wB2 * unpk2(vB.y);
    a45 += wB2 * unpk2(vB.z);
    a67 += wB2 * unpk2(vB.w);
    k = kn;
  }
  for (; k < end; k += 8) {
    int2 e = csr[k];
    uint4 v = *reinterpret_cast<const uint4*>(h1 + (long)e.x * HID + 8 * l8);
    float w = __int_as_float(e.y);
    f32x2 w2v = {w, w};
    a01 += w2v * unpk2(v.x);
    a23 += w2v * unpk2(v.y);
    a45 += w2v * unpk2(v.z);
    a67 += w2v * unpk2(v.w);
  }

  float a0 = a01[0], a1 = a01[1], a2 = a23[0], a3 = a23[1];
  float a4 = a45[0], a5 = a45[1], a6 = a67[0], a7 = a67[1];

  {
    const bool hi = (e8 & 1);
    float s0 = hi ? a0 : a4;  float r0 = __shfl_xor(s0, 8, 64);
    float s1 = hi ? a1 : a5;  float r1 = __shfl_xor(s1, 8, 64);
    float s2 = hi ? a2 : a6;  float r2 = __shfl_xor(s2, 8, 64);
    float s3 = hi ? a3 : a7;  float r3 = __shfl_xor(s3, 8, 64);
    a0 = (hi ? a4 : a0) + r0;
    a1 = (hi ? a5 : a1) + r1;
    a2 = (hi ? a6 : a2) + r2;
    a3 = (hi ? a7 : a3) + r3;
  }
  {
    const bool hi = (e8 >> 1) & 1;
    float s0 = hi ? a0 : a2;  float r0 = __shfl_xor(s0, 16, 64);
    float s1 = hi ? a1 : a3;  float r1 = __shfl_xor(s1, 16, 64);
    a0 = (hi ? a2 : a0) + r0;
    a1 = (hi ? a3 : a1) + r1;
  }
  {
    const bool hi = (e8 >> 2) & 1;
    float s0 = hi ? a0 : a1;  float r0 = __shfl_xor(s0, 32, 64);
    a0 = (hi ? a1 : a0) + r0;
  }
  const int dim = 8 * l8 + 4 * (e8 & 1) + 2 * ((e8 >> 1) & 1) + ((e8 >> 2) & 1);
  float s = fmaxf(a0, 0.f) * W2[dim];
  s += __shfl_xor(s, 1, 64);
  s += __shfl_xor(s, 2, 64);
  s += __shfl_xor(s, 4, 64);
  s += __shfl_xor(s, 8, 64);
  s += __shfl_xor(s, 16, 64);
  s += __shfl_xor(s, 32, 64);
  if (lane == 0) h3[wave] = s + b2[0];
}

// ---------------- Gather spmm2: out[n] = sum_e w*h3[src_e] ----------------
__global__ __launch_bounds__(256) void spmm2_gather_kernel(
    const int* __restrict__ noffs, const int2* __restrict__ csr,
    const float* __restrict__ h3, float* __restrict__ out, int N) {
  int n = blockIdx.x * 256 + threadIdx.x;
  if (n >= N) return;
  int beg = noffs[n], end = noffs[n + 1];
  float acc = 0.f;
  int k = beg;
  if (k < end && (k & 1)) {                       // align to int4
    int2 e = csr[k];
    acc += __int_as_float(e.y) * h3[e.x];
    ++k;
  }
  for (; k + 1 < end; k += 2) {
    int4 e2 = *reinterpret_cast<const int4*>(&csr[k]);
    acc += __int_as_float(e2.y) * h3[e2.x];
    acc += __int_as_float(e2.w) * h3[e2.z];
  }
  if (k < end) {
    int2 e = csr[k];
    acc += __int_as_float(e.y) * h3[e.x];
  }
  out[n] = acc;
}

extern "C" void kernel_launch(void* const* d_in, const int* in_sizes, int n_in,
                              void* d_out, int out_size, void* d_ws, size_t ws_size,
                              hipStream_t stream) {
  const float* x    = (const float*)d_in[0];
  const int*   esrc = (const int*)d_in[1];
  const int*   edst = (const int*)d_in[2];
  const float* ew   = (const float*)d_in[3];
  const float* W1   = (const float*)d_in[4];
  const float* b1   = (const float*)d_in[5];
  const float* W2   = (const float*)d_in[6];
  const float* b2   = (const float*)d_in[7];
  float* out = (float*)d_out;

  const int N = in_sizes[0] / IN_DIM;
  const int E = in_sizes[1];
  const int NB = (N + BNODES - 1) >> SHIFT;         // 391 @ N=100k
  const int NCH = (E + CH - 1) / CH;                // 391 @ E=1.6M

  char* p = (char*)d_ws;
  auto alloc = [&](size_t bytes) {
    char* r = p;
    p += (bytes + 15) & ~(size_t)15;
    return r;
  };
  unsigned short* h1 = (unsigned short*)alloc((size_t)N * HID * sizeof(unsigned short));
  unsigned short* W1b= (unsigned short*)alloc((size_t)8192 * sizeof(unsigned short));
  float* h3          = (float*)alloc((size_t)N * sizeof(float));
  int*   bucket_size = (int*)alloc((size_t)NB * sizeof(int));
  int*   bucket_offs = (int*)alloc((size_t)(NB + 1) * sizeof(int));
  int*   noffs       = (int*)alloc((size_t)(N + 1) * sizeof(int));
  int*   blockRel    = (int*)alloc((size_t)NCH * NB * sizeof(int));
  int2*  bpart       = (int2*)alloc((size_t)E * sizeof(int2));
  int2*  csr         = (int2*)alloc((size_t)E * sizeof(int2));

  w1pack_kernel<<<32, 256, 0, stream>>>(W1, W1b, bucket_size, NB);
  gemm1_kernel<<<(N + 63) / 64, 256, 0, stream>>>(x, W1b, b1, h1, N);

  bucket_count_kernel<<<NCH, 512, 0, stream>>>(edst, bucket_size, blockRel, NB, E, NCH);
  bucket_scan_kernel<<<1, 1024, 0, stream>>>(bucket_size, bucket_offs, NB);
  bucket_place_kernel<<<NCH, 512, 0, stream>>>(esrc, edst, ew, bucket_offs,
                                               blockRel, bpart, NB, E, NCH);
  csr_place_kernel<<<NB, 1024, 0, stream>>>(bpart, bucket_offs, csr, noffs, N, NB, E);

  spmm1_fused_kernel<<<(unsigned)(((long)N * 64 + 255) / 256), 256, 0, stream>>>(
      noffs, csr, h1, W2, b2, h3, N);

  spmm2_gather_kernel<<<(N + 255) / 256, 256, 0, stream>>>(noffs, csr, h3, out, N);
}

// Round 25
// 111.348 us; speedup vs baseline: 1.1875x; 1.0442x over previous
//
#include <hip/hip_runtime.h>

#define IN_DIM 128
#define HID 64
#define SHIFT 8                 // 256 nodes per bucket
#define BNODES 256
#define NBMAX 1024              // NB=391 @ N=100k
#define CH 4096                 // edges per chunk (measured optimum: 2048 ✗, 4096 ✓, 32768 ✗✗)
#define SRCMASK 0xFFFFF         // src packed in low 20 bits (N <= 1M)
#define LDSCAP 6144             // csr_place LDS edge-staging capacity (48 KB)
#define XSTR 130                // Xs row stride in shorts

using bf16x8 = __attribute__((ext_vector_type(8))) short;   // 8 bf16 (4 VGPRs)
using f32x4  = __attribute__((ext_vector_type(4))) float;
using f32x2  = __attribute__((ext_vector_type(2))) float;

// bf16 round-to-nearest-even
__device__ inline unsigned short f2bf(float f) {
  unsigned u = __float_as_uint(f);
  u += 0x7FFF + ((u >> 16) & 1);
  return (unsigned short)(u >> 16);
}
__device__ inline float bf2f_lo(unsigned v) {   // low bf16 of a packed u32
  return __uint_as_float(v << 16);
}
__device__ inline float bf2f_hi(unsigned v) {   // high bf16 of a packed u32
  return __uint_as_float(v & 0xFFFF0000u);
}
__device__ inline f32x2 unpk2(unsigned v) {     // {lo, hi} as f32 pair
  return (f32x2){bf2f_lo(v), bf2f_hi(v)};
}

// R18: bijective XCD-aware block->chunk remap (kept).
__device__ inline int xcd_chunk(int bid, int nch) {
  int q = nch >> 3, r = nch & 7;
  int xcd = bid & 7, idx = bid >> 3;
  return (xcd < r) ? xcd * (q + 1) + idx : r * (q + 1) + (xcd - r) * q + idx;
}

// ---------------- Prep: pack W1 into MFMA B-fragment order + zero counters ----------------
__global__ __launch_bounds__(256) void w1pack_kernel(
    const float* __restrict__ W1, unsigned short* __restrict__ W1b,
    int* __restrict__ bucket_size, int NB) {
  if (blockIdx.x == 0) {
    for (int i = threadIdx.x; i < NB; i += 256) bucket_size[i] = 0;
  }
  int idx = blockIdx.x * 256 + threadIdx.x;   // 8192 total
  if (idx >= 4 * 4 * 64 * 8) return;
  int i    = idx & 7;
  int lane = (idx >> 3) & 63;
  int kc   = (idx >> 9) & 3;
  int jt   = idx >> 11;
  int k = kc * 32 + ((lane >> 4) << 3) + i;
  int n = jt * 16 + (lane & 15);
  W1b[idx] = f2bf(W1[k * HID + n]);
}

// ---------------- Kernel 1: h1 = bf16(x @ W1 + b1) via MFMA ----------------
// R17/R20 structure (proven): coalesced per-wave LDS staging of x, A-frags
// via ds_read_b128, B-frags from pre-packed W1b (L1-resident, uint4/lane).
__global__ __launch_bounds__(256) void gemm1_kernel(
    const float* __restrict__ x, const unsigned short* __restrict__ W1b,
    const float* __restrict__ b1, unsigned short* __restrict__ h1, int N) {
  __shared__ unsigned short Xs[4][16][XSTR];   // 16.6 KB
  const int lane = threadIdx.x & 63;
  const int w    = threadIdx.x >> 6;           // wave id: rows 16w..16w+15
  const int rblk = blockIdx.x * 64;

  for (int it = 0; it < 8; ++it) {
    int flat = it * 64 + lane;                 // 0..511
    int row  = flat >> 5;                      // 32 float4 per row
    int c4   = (flat & 31) * 4;
    int gr = rblk + w * 16 + row;
    if (gr > N - 1) gr = N - 1;
    float4 v = *reinterpret_cast<const float4*>(x + (long)gr * IN_DIM + c4);
    ushort4 o;
    o.x = f2bf(v.x); o.y = f2bf(v.y); o.z = f2bf(v.z); o.w = f2bf(v.w);
    *reinterpret_cast<ushort4*>(&Xs[w][row][c4]) = o;
  }
  __syncthreads();

  bf16x8 a[4];
#pragma unroll
  for (int kc = 0; kc < 4; ++kc) {
    a[kc] = *reinterpret_cast<const bf16x8*>(
        &Xs[w][lane & 15][kc * 32 + ((lane >> 4) << 3)]);
  }

  const uint4* wb = reinterpret_cast<const uint4*>(W1b);
#pragma unroll
  for (int jt = 0; jt < 4; ++jt) {
    f32x4 acc = {0.f, 0.f, 0.f, 0.f};
#pragma unroll
    for (int kc = 0; kc < 4; ++kc) {
      union { uint4 q; bf16x8 v; } bu;
      bu.q = wb[(jt * 4 + kc) * 64 + lane];
      acc = __builtin_amdgcn_mfma_f32_16x16x32_bf16(a[kc], bu.v, acc, 0, 0, 0);
    }
    const int col = jt * 16 + (lane & 15);
    const float bb = b1[col];
#pragma unroll
    for (int r = 0; r < 4; ++r) {
      int row = (lane >> 4) * 4 + r;
      int gr = rblk + w * 16 + row;
      if (gr < N) h1[(long)gr * HID + col] = f2bf(acc[r] + bb);
    }
  }
}

// ------------- Bucket partition pass 1: per-chunk histogram + reservation -------------
// R24: 512 threads.
__global__ __launch_bounds__(512) void bucket_count_kernel(
    const int* __restrict__ dst, int* __restrict__ bucket_size,
    int* __restrict__ blockRel, int NB, int E, int NCH) {
  __shared__ int hist[NBMAX];
  const int c = xcd_chunk(blockIdx.x, NCH);
  for (int i = threadIdx.x; i < NB; i += 512) hist[i] = 0;
  __syncthreads();
  int base = c * CH;
  int end = min(base + CH, E);
  for (int k = base + threadIdx.x * 4; k + 3 < end; k += 2048) {
    int4 d4 = *reinterpret_cast<const int4*>(&dst[k]);
    atomicAdd(&hist[d4.x >> SHIFT], 1);
    atomicAdd(&hist[d4.y >> SHIFT], 1);
    atomicAdd(&hist[d4.z >> SHIFT], 1);
    atomicAdd(&hist[d4.w >> SHIFT], 1);
  }
  int tail_start = base + ((end - base) & ~3);
  for (int k = tail_start + threadIdx.x; k < end; k += 512)
    atomicAdd(&hist[dst[k] >> SHIFT], 1);
  __syncthreads();
  for (int i = threadIdx.x; i < NB; i += 512) {
    int cv = hist[i];
    int r = cv ? atomicAdd(&bucket_size[i], cv) : 0;
    blockRel[(long)c * NB + i] = r;
  }
}

// ------------- Pass 2(+3): place edges; per-block LOCAL scan of bucket_size -------------
// R25: scan kernel folded in. Each block re-scans the NB-entry bucket_size
// array in LDS (1.6 KB, L2-hot, ~30 instr) -> removes one launch + gap.
// Block 0 publishes bucket_offs for csr_place. NB <= 512 required (391 ok).
__global__ __launch_bounds__(512) void bucket_place_kernel(
    const int* __restrict__ src, const int* __restrict__ dst,
    const float* __restrict__ w, const int* __restrict__ bucket_size,
    const int* __restrict__ blockRel, int* __restrict__ bucket_offs,
    int2* __restrict__ bpart, int NB, int E, int NCH) {
  __shared__ int cur[NBMAX];
  __shared__ int wtot[8];
  const int t = threadIdx.x;
  const int c = xcd_chunk(blockIdx.x, NCH);

  // local exclusive scan of bucket_size[0..NB) (NB <= 512, one pass)
  int v = (t < NB) ? bucket_size[t] : 0;
  int s = v;
#pragma unroll
  for (int d = 1; d < 64; d <<= 1) {
    int u = __shfl_up(s, d, 64);
    if ((t & 63) >= d) s += u;
  }
  if ((t & 63) == 63) wtot[t >> 6] = s;
  __syncthreads();
  int basew = 0;
  const int wv_ = t >> 6;
#pragma unroll
  for (int i = 0; i < 7; ++i)
    if (wv_ > i) basew += wtot[i];
  const int offs = basew + s - v;             // exclusive prefix for bucket t
  if (t < NB) {
    cur[t] = offs + blockRel[(long)c * NB + t];
    if (blockIdx.x == 0) bucket_offs[t] = offs;
  }
  if (blockIdx.x == 0 && t == 0) bucket_offs[NB] = E;
  __syncthreads();

  int base = c * CH;
  int end = min(base + CH, E);
  for (int k = base + t * 4; k + 3 < end; k += 2048) {
    int4   s4 = *reinterpret_cast<const int4*>(&src[k]);
    int4   d4 = *reinterpret_cast<const int4*>(&dst[k]);
    float4 w4 = *reinterpret_cast<const float4*>(&w[k]);
    int p0 = atomicAdd(&cur[d4.x >> SHIFT], 1);
    int p1 = atomicAdd(&cur[d4.y >> SHIFT], 1);
    int p2 = atomicAdd(&cur[d4.z >> SHIFT], 1);
    int p3 = atomicAdd(&cur[d4.w >> SHIFT], 1);
    bpart[p0] = make_int2((s4.x & SRCMASK) | ((d4.x & (BNODES - 1)) << 20),
                          __float_as_int(w4.x));
    bpart[p1] = make_int2((s4.y & SRCMASK) | ((d4.y & (BNODES - 1)) << 20),
                          __float_as_int(w4.y));
    bpart[p2] = make_int2((s4.z & SRCMASK) | ((d4.z & (BNODES - 1)) << 20),
                          __float_as_int(w4.z));
    bpart[p3] = make_int2((s4.w & SRCMASK) | ((d4.w & (BNODES - 1)) << 20),
                          __float_as_int(w4.w));
  }
  int tail_start = base + ((end - base) & ~3);
  for (int k = tail_start + t; k < end; k += 512) {
    int d = dst[k];
    int b = d >> SHIFT;
    int pos = atomicAdd(&cur[b], 1);
    bpart[pos] = make_int2((src[k] & SRCMASK) | ((d & (BNODES - 1)) << 20),
                           __float_as_int(w[k]));
  }
}

// ------------- Pass 4: per-bucket CSR finalize (LDS-staged, 1024 thr) -------------
__global__ __launch_bounds__(1024) void csr_place_kernel(
    const int2* __restrict__ bpart, const int* __restrict__ bucket_offs,
    int2* __restrict__ csr, int* __restrict__ noffs, int N, int NB, int E) {
  __shared__ int cnt[BNODES];
  __shared__ int cur[BNODES];
  __shared__ int wtot[4];
  __shared__ int2 ebuf[LDSCAP];
  const int t = threadIdx.x;
  const int b = blockIdx.x;
  const int beg = bucket_offs[b], end = bucket_offs[b + 1];
  const int len = end - beg;
  const bool useLds = (len <= LDSCAP);

  if (t < BNODES) cnt[t] = 0;
  __syncthreads();

  if (useLds) {
    for (int k = t; k < len; k += 1024) {
      int2 e = bpart[beg + k];
      ebuf[k] = e;
      atomicAdd(&cnt[e.x >> 20], 1);
    }
  } else {
    for (int k = beg + t; k < end; k += 1024)
      atomicAdd(&cnt[bpart[k].x >> 20], 1);
  }
  __syncthreads();

  int v = (t < BNODES) ? cnt[t] : 0;
  int s = v;
#pragma unroll
  for (int d = 1; d < 64; d <<= 1) {
    int u = __shfl_up(s, d, 64);
    if ((t & 63) >= d) s += u;
  }
  if (t < BNODES && (t & 63) == 63) wtot[t >> 6] = s;
  __syncthreads();
  if (t < BNODES) {
    int base = 0;
    const int wv_ = t >> 6;
    if (wv_ > 0) base += wtot[0];
    if (wv_ > 1) base += wtot[1];
    if (wv_ > 2) base += wtot[2];
    const int g = beg + base + s - v;  // global exclusive offset for node t
    cur[t] = g;
    const int node = (b << SHIFT) + t;
    if (node < N) noffs[node] = g;
  }
  if (b == NB - 1 && t == 0) noffs[N] = E;
  __syncthreads();

  if (useLds) {
    for (int k = t; k < len; k += 1024) {
      int2 e = ebuf[k];
      int pos = atomicAdd(&cur[e.x >> 20], 1);
      csr[pos] = make_int2(e.x & SRCMASK, e.y);
    }
  } else {
    for (int k = beg + t; k < end; k += 1024) {
      int2 e = bpart[k];
      int pos = atomicAdd(&cur[e.x >> 20], 1);
      csr[pos] = make_int2(e.x & SRCMASK, e.y);
    }
  }
}

// ---------------- Fused: h3[n] = relu(sum_e w*h1[src_e]) . W2 + b2 ----------------
// R13 structure + R21 f32x2. At its L2-fill roofline (83 MB @ ~2 TB/s).
__global__ __launch_bounds__(256) void spmm1_fused_kernel(
    const int* __restrict__ noffs, const int2* __restrict__ csr,
    const unsigned short* __restrict__ h1, const float* __restrict__ W2,
    const float* __restrict__ b2, float* __restrict__ h3, int N) {
  int wave = (blockIdx.x * 256 + threadIdx.x) >> 6;
  int lane = threadIdx.x & 63;
  if (wave >= N) return;
  int beg = noffs[wave], end = noffs[wave + 1];
  const int e8 = lane >> 3;        // eighth 0..7 (edge subset)
  const int l8 = lane & 7;         // dim group: dims 8*l8 .. 8*l8+7

  f32x2 a01 = {0.f, 0.f}, a23 = {0.f, 0.f};
  f32x2 a45 = {0.f, 0.f}, a67 = {0.f, 0.f};
  int k = beg + e8;

  int2 eA, eB;
  if (k + 8 < end) { eA = csr[k]; eB = csr[k + 8]; }
  while (k + 8 < end) {
    uint4 vA = *reinterpret_cast<const uint4*>(h1 + (long)eA.x * HID + 8 * l8);
    uint4 vB = *reinterpret_cast<const uint4*>(h1 + (long)eB.x * HID + 8 * l8);
    float wA = __int_as_float(eA.y), wB = __int_as_float(eB.y);
    int kn = k + 16;
    if (kn + 8 < end) { eA = csr[kn]; eB = csr[kn + 8]; }  // prefetch next pair
    f32x2 wA2 = {wA, wA}, wB2 = {wB, wB};
    a01 += wA2 * unpk2(vA.x);
    a23 += wA2 * unpk2(vA.y);
    a45 += wA2 * unpk2(vA.z);
    a67 += wA2 * unpk2(vA.w);
    a01 += wB2 * unpk2(vB.x);
    a23 += wB2 * unpk2(vB.y);
    a45 += wB2 * unpk2(vB.z);
    a67 += wB2 * unpk2(vB.w);
    k = kn;
  }
  for (; k < end; k += 8) {
    int2 e = csr[k];
    uint4 v = *reinterpret_cast<const uint4*>(h1 + (long)e.x * HID + 8 * l8);
    float w = __int_as_float(e.y);
    f32x2 w2v = {w, w};
    a01 += w2v * unpk2(v.x);
    a23 += w2v * unpk2(v.y);
    a45 += w2v * unpk2(v.z);
    a67 += w2v * unpk2(v.w);
  }

  float a0 = a01[0], a1 = a01[1], a2 = a23[0], a3 = a23[1];
  float a4 = a45[0], a5 = a45[1], a6 = a67[0], a7 = a67[1];

  {
    const bool hi = (e8 & 1);
    float s0 = hi ? a0 : a4;  float r0 = __shfl_xor(s0, 8, 64);
    float s1 = hi ? a1 : a5;  float r1 = __shfl_xor(s1, 8, 64);
    float s2 = hi ? a2 : a6;  float r2 = __shfl_xor(s2, 8, 64);
    float s3 = hi ? a3 : a7;  float r3 = __shfl_xor(s3, 8, 64);
    a0 = (hi ? a4 : a0) + r0;
    a1 = (hi ? a5 : a1) + r1;
    a2 = (hi ? a6 : a2) + r2;
    a3 = (hi ? a7 : a3) + r3;
  }
  {
    const bool hi = (e8 >> 1) & 1;
    float s0 = hi ? a0 : a2;  float r0 = __shfl_xor(s0, 16, 64);
    float s1 = hi ? a1 : a3;  float r1 = __shfl_xor(s1, 16, 64);
    a0 = (hi ? a2 : a0) + r0;
    a1 = (hi ? a3 : a1) + r1;
  }
  {
    const bool hi = (e8 >> 2) & 1;
    float s0 = hi ? a0 : a1;  float r0 = __shfl_xor(s0, 32, 64);
    a0 = (hi ? a1 : a0) + r0;
  }
  const int dim = 8 * l8 + 4 * (e8 & 1) + 2 * ((e8 >> 1) & 1) + ((e8 >> 2) & 1);
  float s = fmaxf(a0, 0.f) * W2[dim];
  s += __shfl_xor(s, 1, 64);
  s += __shfl_xor(s, 2, 64);
  s += __shfl_xor(s, 4, 64);
  s += __shfl_xor(s, 8, 64);
  s += __shfl_xor(s, 16, 64);
  s += __shfl_xor(s, 32, 64);
  if (lane == 0) h3[wave] = s + b2[0];
}

// ---------------- Gather spmm2: out[n] = sum_e w*h3[src_e] ----------------
// R25: eight lanes per node (R24 thread-per-node had 391 blocks = 1.5/CU and
// ~16 serial dependent loads/thread). Each lane walks k=beg+l8 step 8 (~2
// iters at deg~16); 3-shfl group reduce. 3125 blocks.
__global__ __launch_bounds__(256) void spmm2_gather_kernel(
    const int* __restrict__ noffs, const int2* __restrict__ csr,
    const float* __restrict__ h3, float* __restrict__ out, int N) {
  int gid = (blockIdx.x * 256 + threadIdx.x) >> 3;   // node id
  int l8  = threadIdx.x & 7;
  if (gid >= N) return;
  int beg = noffs[gid], end = noffs[gid + 1];
  float acc = 0.f;
  for (int k = beg + l8; k < end; k += 8) {
    int2 e = csr[k];
    acc += __int_as_float(e.y) * h3[e.x];
  }
  acc += __shfl_xor(acc, 1, 64);
  acc += __shfl_xor(acc, 2, 64);
  acc += __shfl_xor(acc, 4, 64);
  if (l8 == 0) out[gid] = acc;
}

extern "C" void kernel_launch(void* const* d_in, const int* in_sizes, int n_in,
                              void* d_out, int out_size, void* d_ws, size_t ws_size,
                              hipStream_t stream) {
  const float* x    = (const float*)d_in[0];
  const int*   esrc = (const int*)d_in[1];
  const int*   edst = (const int*)d_in[2];
  const float* ew   = (const float*)d_in[3];
  const float* W1   = (const float*)d_in[4];
  const float* b1   = (const float*)d_in[5];
  const float* W2   = (const float*)d_in[6];
  const float* b2   = (const float*)d_in[7];
  float* out = (float*)d_out;

  const int N = in_sizes[0] / IN_DIM;
  const int E = in_sizes[1];
  const int NB = (N + BNODES - 1) >> SHIFT;         // 391 @ N=100k (must be <= 512)
  const int NCH = (E + CH - 1) / CH;                // 391 @ E=1.6M

  char* p = (char*)d_ws;
  auto alloc = [&](size_t bytes) {
    char* r = p;
    p += (bytes + 15) & ~(size_t)15;
    return r;
  };
  unsigned short* h1 = (unsigned short*)alloc((size_t)N * HID * sizeof(unsigned short));
  unsigned short* W1b= (unsigned short*)alloc((size_t)8192 * sizeof(unsigned short));
  float* h3          = (float*)alloc((size_t)N * sizeof(float));
  int*   bucket_size = (int*)alloc((size_t)NB * sizeof(int));
  int*   bucket_offs = (int*)alloc((size_t)(NB + 1) * sizeof(int));
  int*   noffs       = (int*)alloc((size_t)(N + 1) * sizeof(int));
  int*   blockRel    = (int*)alloc((size_t)NCH * NB * sizeof(int));
  int2*  bpart       = (int2*)alloc((size_t)E * sizeof(int2));
  int2*  csr         = (int2*)alloc((size_t)E * sizeof(int2));

  w1pack_kernel<<<32, 256, 0, stream>>>(W1, W1b, bucket_size, NB);
  gemm1_kernel<<<(N + 63) / 64, 256, 0, stream>>>(x, W1b, b1, h1, N);

  bucket_count_kernel<<<NCH, 512, 0, stream>>>(edst, bucket_size, blockRel, NB, E, NCH);
  bucket_place_kernel<<<NCH, 512, 0, stream>>>(esrc, edst, ew, bucket_size,
                                               blockRel, bucket_offs, bpart,
                                               NB, E, NCH);
  csr_place_kernel<<<NB, 1024, 0, stream>>>(bpart, bucket_offs, csr, noffs, N, NB, E);

  spmm1_fused_kernel<<<(unsigned)(((long)N * 64 + 255) / 256), 256, 0, stream>>>(
      noffs, csr, h1, W2, b2, h3, N);

  spmm2_gather_kernel<<<(unsigned)(((long)N * 8 + 255) / 256), 256, 0, stream>>>(
      noffs, csr, h3, out, N);
}